// Round 10
// baseline (80.934 us; speedup 1.0000x reference)
//
#include <hip/hip_runtime.h>

typedef unsigned short u16;
typedef __bf16 bf16x8 __attribute__((ext_vector_type(8)));
typedef float f32x4 __attribute__((ext_vector_type(4)));
typedef unsigned short u16x8 __attribute__((ext_vector_type(8)));

#define DIM 512
#define EPSV 1e-6f
#define MARGIN 0.2f
#define DEPS2 (512.0f * 1e-6f * 1e-6f)
#define BK 32
#define NSLICE (DIM / BK)   // 16
#define RING 3

#define AS1 __attribute__((address_space(1)))
#define AS3 __attribute__((address_space(3)))

__device__ __forceinline__ u16 f2bf(float f) {
    unsigned int u = __float_as_uint(f);
    unsigned int r = (u + 0x7fffu + ((u >> 16) & 1u)) >> 16;
    return (u16)r;
}

// ---------------- Kernel 1: per-row stats + bf16 convert ----------------
__global__ __launch_bounds__(256) void prep_kernel(
        const float* __restrict__ A, const float* __restrict__ P,
        u16* __restrict__ Abf, float* __restrict__ alpha,
        float* __restrict__ beta, float* __restrict__ dap,
        unsigned int* __restrict__ dan2, int N) {
    int row = blockIdx.x * 4 + (threadIdx.x >> 6);
    int lane = threadIdx.x & 63;
    if (row >= N) return;
    const float* a = A + (size_t)row * DIM + lane * 8;
    const float* p = P + (size_t)row * DIM + lane * 8;
    float4 a0 = *(const float4*)(a);
    float4 a1 = *(const float4*)(a + 4);
    float4 p0 = *(const float4*)(p);
    float4 p1 = *(const float4*)(p + 4);
    float av[8] = {a0.x, a0.y, a0.z, a0.w, a1.x, a1.y, a1.z, a1.w};
    float pv[8] = {p0.x, p0.y, p0.z, p0.w, p1.x, p1.y, p1.z, p1.w};
    float sq = 0.f, s = 0.f, dp = 0.f;
    u16x8 ob;
    #pragma unroll
    for (int e = 0; e < 8; ++e) {
        float x = av[e];
        sq = fmaf(x, x, sq);
        s += x;
        float d = x - pv[e] + EPSV;
        dp = fmaf(d, d, dp);
        ob[e] = f2bf(x);
    }
    *reinterpret_cast<u16x8*>(Abf + (size_t)row * DIM + lane * 8) = ob;
    #pragma unroll
    for (int mask = 32; mask; mask >>= 1) {
        sq += __shfl_xor(sq, mask, 64);
        s  += __shfl_xor(s,  mask, 64);
        dp += __shfl_xor(dp, mask, 64);
    }
    if (lane == 0) {
        alpha[row] = fmaf(2.0f * EPSV, s, sq);
        beta[row]  = fmaf(-2.0f * EPSV, s, sq);
        dap[row]   = sqrtf(dp);
        dan2[row]  = 0x7f800000u;   // +inf
    }
}

// ---------------- Kernel 2: 256^2 ring-3 PHASE-SPLIT Gram + row/col min ----------------
// r3 chassis (verified): 512 thr = 8 waves (2M x 4N), per-wave 128x64 = acc[8][4];
// LDS ring-3 x {A,B} x 8192 u16, granule-rotation swizzle (0 conflicts), staging
// via inverse-rotated global source, counted vmcnt(4) per slice.
// NEW: each slice split into 2 template phases {reads; 2 gloads; barrier;
// setprio1; 16 MFMA; setprio0; barrier} -- within-block role-split (T3+T5).
__global__ __launch_bounds__(512, 2) void gemm_min_kernel(
        const u16* __restrict__ Abf, const float* __restrict__ alpha,
        const float* __restrict__ beta, unsigned int* __restrict__ dan2, int N) {

    __shared__ u16 lds[RING][2][8192];   // 96 KiB

    // XCD-chunked bijective swizzle: 528 = 8 * 66
    int orig = blockIdx.x;
    int b = (orig & 7) * 66 + (orig >> 3);

    // triangular block index -> (it, jt), it <= jt
    int jt = (int)((sqrtf(8.0f * (float)b + 1.0f) - 1.0f) * 0.5f);
    while ((jt + 1) * (jt + 2) / 2 <= b) ++jt;
    while (jt * (jt + 1) / 2 > b) --jt;
    int it = b - jt * (jt + 1) / 2;
    bool diag = (it == jt);
    int ibase = it << 8, jbase = jt << 8;

    int tid = threadIdx.x;
    int wave = tid >> 6, lane = tid & 63;
    int wr = wave >> 2, wc = wave & 3;      // 2 x 4 wave grid
    int g = lane >> 4, tl = lane & 15;

    // staging (r3-verified): inverse granule rotation on global source
    int gsrc = ((lane & 3) - ((lane >> 3) & 3)) & 3;
    auto stage_half = [&](int s, int slot, int j) {
        int ks = s * BK;
        int gbase = j * 8 + wave;                 // 0..15 (wave-uniform)
        int row = gbase * 16 + (lane >> 2);       // 0..255
        const u16* srcA = Abf + (size_t)(ibase + row) * DIM + ks + gsrc * 8;
        __builtin_amdgcn_global_load_lds(
            (const AS1 void*)srcA,
            (AS3 void*)&lds[slot][0][gbase * 512], 16, 0, 0);
        const u16* srcB = Abf + (size_t)(jbase + row) * DIM + ks + gsrc * 8;
        __builtin_amdgcn_global_load_lds(
            (const AS1 void*)srcB,
            (AS3 void*)&lds[slot][1][gbase * 512], 16, 0, 0);
    };

    // per-lane swizzled read offsets (u16 units), constant across slices
    int swz = (g + ((tl >> 1) & 3)) & 3;
    int aOff[8], bOff[4];
    #pragma unroll
    for (int mf = 0; mf < 8; ++mf)
        aOff[mf] = (wr * 128 + mf * 16 + tl) * 32 + swz * 8;
    #pragma unroll
    for (int nf = 0; nf < 4; ++nf)
        bOff[nf] = (wc * 64 + nf * 16 + tl) * 32 + swz * 8;

    f32x4 acc[8][4];
    f32x4 zero = {0.f, 0.f, 0.f, 0.f};
    #pragma unroll
    for (int mf = 0; mf < 8; ++mf)
        #pragma unroll
        for (int nf = 0; nf < 4; ++nf) acc[mf][nf] = zero;

    // ---- prologue: stage slices 0,1; certify 0 (slice 1's 4 loads in flight) ----
    stage_half(0, 0, 0); stage_half(0, 0, 1);
    stage_half(1, 1, 0); stage_half(1, 1, 1);
    asm volatile("s_waitcnt vmcnt(4)" ::: "memory");
    __builtin_amdgcn_s_barrier();
    __builtin_amdgcn_sched_barrier(0);

    #pragma unroll
    for (int t = 0; t < NSLICE; ++t) {
        const int slot = t % RING;
        const u16* As = &lds[slot][0][0];
        const u16* Bs = &lds[slot][1][0];

        // ================ phase 1: m0-3 x n0-3 ================
        bf16x8 af[4], bfr[4];
        #pragma unroll
        for (int mf = 0; mf < 4; ++mf)
            af[mf] = *reinterpret_cast<const bf16x8*>(As + aOff[mf]);
        #pragma unroll
        for (int nf = 0; nf < 4; ++nf)
            bfr[nf] = *reinterpret_cast<const bf16x8*>(Bs + bOff[nf]);
        if (t + 2 < NSLICE) stage_half(t + 2, (t + 2) % RING, 0);
        __builtin_amdgcn_s_barrier();
        __builtin_amdgcn_s_setprio(1);
        #pragma unroll
        for (int mf = 0; mf < 4; ++mf)
            #pragma unroll
            for (int nf = 0; nf < 4; ++nf)
                acc[mf][nf] = __builtin_amdgcn_mfma_f32_16x16x32_bf16(
                    af[mf], bfr[nf], acc[mf][nf], 0, 0, 0);
        __builtin_amdgcn_s_setprio(0);
        __builtin_amdgcn_s_barrier();

        // ================ phase 2: m4-7 x n0-3 ================
        bf16x8 af2[4];
        #pragma unroll
        for (int mf = 0; mf < 4; ++mf)
            af2[mf] = *reinterpret_cast<const bf16x8*>(As + aOff[mf + 4]);
        if (t + 2 < NSLICE) stage_half(t + 2, (t + 2) % RING, 1);
        if (t + 1 < NSLICE) {
            // counted: retire slice t+1's 4 loads; slice t+2's 4 stay in flight
            if (t + 2 < NSLICE) { asm volatile("s_waitcnt vmcnt(4)" ::: "memory"); }
            else                { asm volatile("s_waitcnt vmcnt(0)" ::: "memory"); }
            __builtin_amdgcn_s_barrier();
        }
        __builtin_amdgcn_s_setprio(1);
        #pragma unroll
        for (int mf = 0; mf < 4; ++mf)
            #pragma unroll
            for (int nf = 0; nf < 4; ++nf)
                acc[mf + 4][nf] = __builtin_amdgcn_mfma_f32_16x16x32_bf16(
                    af2[mf], bfr[nf], acc[mf + 4][nf], 0, 0, 0);
        __builtin_amdgcn_s_setprio(0);
        if (t + 1 < NSLICE) {
            __builtin_amdgcn_s_barrier();          // all reads of slot t retired
            __builtin_amdgcn_sched_barrier(0);     // fence stage-issue hoisting (r3)
        }
    }

    const float INF = __builtin_inff();

    // ---- row-side epilogue (r3-verified): rows I, min over 256 cols ----
    float bb[4];
    #pragma unroll
    for (int nf = 0; nf < 4; ++nf) bb[nf] = beta[jbase + wc * 64 + nf * 16 + tl];

    #pragma unroll
    for (int mf = 0; mf < 8; ++mf) {
        int grow0 = ibase + wr * 128 + mf * 16 + g * 4;
        float mn0 = INF, mn1 = INF, mn2 = INF, mn3 = INF;
        #pragma unroll
        for (int nf = 0; nf < 4; ++nf) {
            int gcol = jbase + wc * 64 + nf * 16 + tl;
            float c0 = fmaf(-2.f, acc[mf][nf][0], bb[nf]);
            float c1 = fmaf(-2.f, acc[mf][nf][1], bb[nf]);
            float c2 = fmaf(-2.f, acc[mf][nf][2], bb[nf]);
            float c3 = fmaf(-2.f, acc[mf][nf][3], bb[nf]);
            if (diag) {
                if (grow0 + 0 == gcol) c0 = INF;
                if (grow0 + 1 == gcol) c1 = INF;
                if (grow0 + 2 == gcol) c2 = INF;
                if (grow0 + 3 == gcol) c3 = INF;
            }
            mn0 = fminf(mn0, c0);
            mn1 = fminf(mn1, c1);
            mn2 = fminf(mn2, c2);
            mn3 = fminf(mn3, c3);
        }
        #pragma unroll
        for (int mask = 1; mask < 16; mask <<= 1) {
            mn0 = fminf(mn0, __shfl_xor(mn0, mask, 64));
            mn1 = fminf(mn1, __shfl_xor(mn1, mask, 64));
            mn2 = fminf(mn2, __shfl_xor(mn2, mask, 64));
            mn3 = fminf(mn3, __shfl_xor(mn3, mask, 64));
        }
        if (tl == 0) {
            float d20 = fmaxf(alpha[grow0 + 0] + DEPS2 + mn0, 0.f);
            float d21 = fmaxf(alpha[grow0 + 1] + DEPS2 + mn1, 0.f);
            float d22 = fmaxf(alpha[grow0 + 2] + DEPS2 + mn2, 0.f);
            float d23 = fmaxf(alpha[grow0 + 3] + DEPS2 + mn3, 0.f);
            atomicMin(dan2 + grow0 + 0, __float_as_uint(d20));
            atomicMin(dan2 + grow0 + 1, __float_as_uint(d21));
            atomicMin(dan2 + grow0 + 2, __float_as_uint(d22));
            atomicMin(dan2 + grow0 + 3, __float_as_uint(d23));
        }
    }

    // ---- col-side epilogue (off-diag only, r3-verified) ----
    if (!diag) {
        #pragma unroll
        for (int nf = 0; nf < 4; ++nf) {
            float cm = INF;
            #pragma unroll
            for (int mf = 0; mf < 8; ++mf) {
                int grow0 = ibase + wr * 128 + mf * 16 + g * 4;
                float b0 = beta[grow0 + 0];
                float b1 = beta[grow0 + 1];
                float b2 = beta[grow0 + 2];
                float b3 = beta[grow0 + 3];
                cm = fminf(cm, fmaf(-2.f, acc[mf][nf][0], b0));
                cm = fminf(cm, fmaf(-2.f, acc[mf][nf][1], b1));
                cm = fminf(cm, fmaf(-2.f, acc[mf][nf][2], b2));
                cm = fminf(cm, fmaf(-2.f, acc[mf][nf][3], b3));
            }
            cm = fminf(cm, __shfl_xor(cm, 16, 64));
            cm = fminf(cm, __shfl_xor(cm, 32, 64));
            if (g == 0) {
                int gcol = jbase + wc * 64 + nf * 16 + tl;
                float d2 = fmaxf(alpha[gcol] + DEPS2 + cm, 0.f);
                atomicMin(dan2 + gcol, __float_as_uint(d2));
            }
        }
    }
}

// ---------------- Kernel 3: final loss reduction ----------------
__global__ __launch_bounds__(1024) void finalize_kernel(
        const float* __restrict__ dap, const unsigned int* __restrict__ dan2,
        float* __restrict__ out, int N) {
    __shared__ float red[16];
    float sum = 0.f;
    for (int i = threadIdx.x; i < N; i += 1024) {
        float dan = sqrtf(__uint_as_float(dan2[i]));
        float v = dap[i] - dan + MARGIN;
        sum += fmaxf(v, 0.f);
    }
    #pragma unroll
    for (int mask = 32; mask; mask >>= 1) sum += __shfl_xor(sum, mask, 64);
    int lane = threadIdx.x & 63, w = threadIdx.x >> 6;
    if (lane == 0) red[w] = sum;
    __syncthreads();
    if (threadIdx.x == 0) {
        float tot = 0.f;
        #pragma unroll
        for (int k = 0; k < 16; ++k) tot += red[k];
        out[0] = tot / (float)N;
    }
}

extern "C" void kernel_launch(void* const* d_in, const int* in_sizes, int n_in,
                              void* d_out, int out_size, void* d_ws, size_t ws_size,
                              hipStream_t stream) {
    const float* anchor   = (const float*)d_in[0];
    const float* positive = (const float*)d_in[1];
    int N = in_sizes[0] / DIM;   // 8192
    float* out = (float*)d_out;

    char* ws = (char*)d_ws;
    float* alpha = (float*)ws;
    float* beta  = alpha + N;
    float* dap   = beta + N;
    unsigned int* dan2 = (unsigned int*)(dap + N);
    u16* Abf = (u16*)(dan2 + N);   // N*DIM bf16 = 8.4 MB

    prep_kernel<<<N / 4, 256, 0, stream>>>(anchor, positive, Abf, alpha, beta, dap, dan2, N);
    int nbt = N >> 8;                     // 32 tiles of 256
    int ntri = nbt * (nbt + 1) / 2;       // 528 blocks (= 8 * 66), it <= jt
    gemm_min_kernel<<<ntri, 512, 0, stream>>>(Abf, alpha, beta, dan2, N);
    finalize_kernel<<<1, 1024, 0, stream>>>(dap, dan2, out, N);
}

// Round 11
// 69.950 us; speedup vs baseline: 1.1570x; 1.1570x over previous
//
#include <hip/hip_runtime.h>

typedef unsigned short u16;
typedef __bf16 bf16x8 __attribute__((ext_vector_type(8)));
typedef float f32x4 __attribute__((ext_vector_type(4)));
typedef unsigned short u16x8 __attribute__((ext_vector_type(8)));

#define DIM 512
#define EPSV 1e-6f
#define MARGIN 0.2f
#define DEPS2 (512.0f * 1e-6f * 1e-6f)
#define BK 32
#define NSLICE (DIM / BK)   // 16
#define RING 3

#define AS1 __attribute__((address_space(1)))
#define AS3 __attribute__((address_space(3)))

__device__ __forceinline__ u16 f2bf(float f) {
    unsigned int u = __float_as_uint(f);
    unsigned int r = (u + 0x7fffu + ((u >> 16) & 1u)) >> 16;
    return (u16)r;
}

// ---------------- Kernel 1: per-row stats + bf16 convert ----------------
__global__ __launch_bounds__(256) void prep_kernel(
        const float* __restrict__ A, const float* __restrict__ P,
        u16* __restrict__ Abf, float* __restrict__ alpha,
        float* __restrict__ beta, float* __restrict__ dap,
        unsigned int* __restrict__ dan2, int N) {
    int row = blockIdx.x * 4 + (threadIdx.x >> 6);
    int lane = threadIdx.x & 63;
    if (row >= N) return;
    const float* a = A + (size_t)row * DIM + lane * 8;
    const float* p = P + (size_t)row * DIM + lane * 8;
    float4 a0 = *(const float4*)(a);
    float4 a1 = *(const float4*)(a + 4);
    float4 p0 = *(const float4*)(p);
    float4 p1 = *(const float4*)(p + 4);
    float av[8] = {a0.x, a0.y, a0.z, a0.w, a1.x, a1.y, a1.z, a1.w};
    float pv[8] = {p0.x, p0.y, p0.z, p0.w, p1.x, p1.y, p1.z, p1.w};
    float sq = 0.f, s = 0.f, dp = 0.f;
    u16x8 ob;
    #pragma unroll
    for (int e = 0; e < 8; ++e) {
        float x = av[e];
        sq = fmaf(x, x, sq);
        s += x;
        float d = x - pv[e] + EPSV;
        dp = fmaf(d, d, dp);
        ob[e] = f2bf(x);
    }
    *reinterpret_cast<u16x8*>(Abf + (size_t)row * DIM + lane * 8) = ob;
    #pragma unroll
    for (int mask = 32; mask; mask >>= 1) {
        sq += __shfl_xor(sq, mask, 64);
        s  += __shfl_xor(s,  mask, 64);
        dp += __shfl_xor(dp, mask, 64);
    }
    if (lane == 0) {
        alpha[row] = fmaf(2.0f * EPSV, s, sq);
        beta[row]  = fmaf(-2.0f * EPSV, s, sq);
        dap[row]   = sqrtf(dp);
        dan2[row]  = 0x7f800000u;   // +inf
    }
}

// ---------------- Kernel 2: 128x128 triangular ring-3 Gram + row/col min ----------------
// Tiles (it,jt), it <= jt over 64x64 tile grid: 2080 blocks (= 8*260).
// 4 waves (2x2), per-wave 64x64 = acc[4][4] of 16x16 frags (64 regs; 128 total
// per wave with addr -> 4 waves/SIMD reg-wise). LDS ring-3 x {A[128][32],
// B[128][32]} u16 with granule rotation (r3/r7-verified, 0 conflicts); 48 KB
// -> 3 blocks/CU = 3 INDEPENDENT barrier groups (the r10 lesson: bubbles are
// hidden by co-resident blocks, not intra-block phases).
__global__ __launch_bounds__(256, 3) void gemm_min_kernel(
        const u16* __restrict__ Abf, const float* __restrict__ alpha,
        const float* __restrict__ beta, unsigned int* __restrict__ dan2, int N) {

    __shared__ u16 lds[RING][8192];   // 48 KiB: per slot A=4096 u16, B=4096 u16

    // XCD-chunked bijective swizzle: 2080 = 8 * 260
    int orig = blockIdx.x;
    int b = (orig & 7) * 260 + (orig >> 3);

    // triangular decode b -> (it, jt), it <= jt (jt-major: consecutive share jt)
    int jt = (int)((sqrtf(8.0f * (float)b + 1.0f) - 1.0f) * 0.5f);
    while ((jt + 1) * (jt + 2) / 2 <= b) ++jt;
    while (jt * (jt + 1) / 2 > b) --jt;
    int it = b - jt * (jt + 1) / 2;
    bool diag = (it == jt);
    int ibase = it << 7, jbase = jt << 7;

    int tid = threadIdx.x;
    int wave = tid >> 6, lane = tid & 63;
    int wr = wave >> 1, wc = wave & 1;      // 2 x 2 wave grid, 64x64 per wave
    int g = lane >> 4, tl = lane & 15;

    // staging (r7-verified pattern): lane -> (row = base + lane>>2, slot p = lane&3);
    // source granule = inverse rotation
    int srow = lane >> 2;
    int gsrc = ((lane & 3) - ((lane >> 3) & 3)) & 3;
    const u16* pA0 = Abf + (size_t)(ibase + wave * 32 + srow) * DIM + gsrc * 8;
    const u16* pA1 = Abf + (size_t)(ibase + wave * 32 + 16 + srow) * DIM + gsrc * 8;
    const u16* pB0 = Abf + (size_t)(jbase + wave * 32 + srow) * DIM + gsrc * 8;
    const u16* pB1 = Abf + (size_t)(jbase + wave * 32 + 16 + srow) * DIM + gsrc * 8;

    // ds_read offsets (u16): row r granule-slot p at r*32 + p*8, p=(g+(tl>>1)&3)&3
    int swz = (g + ((tl >> 1) & 3)) & 3;
    int aOff[4], bOff[4];
    #pragma unroll
    for (int mf = 0; mf < 4; ++mf)
        aOff[mf] = (wr * 64 + mf * 16 + tl) * 32 + swz * 8;
    #pragma unroll
    for (int nf = 0; nf < 4; ++nf)
        bOff[nf] = 4096 + (wc * 64 + nf * 16 + tl) * 32 + swz * 8;

    f32x4 acc[4][4];
    f32x4 zero = {0.f, 0.f, 0.f, 0.f};
    #pragma unroll
    for (int mf = 0; mf < 4; ++mf)
        #pragma unroll
        for (int nf = 0; nf < 4; ++nf) acc[mf][nf] = zero;

    auto stage = [&](int t, int slot) {
        u16* base = &lds[slot][0];
        __builtin_amdgcn_global_load_lds((const AS1 void*)(pA0 + t * BK),
            (AS3 void*)(base + wave * 1024), 16, 0, 0);
        __builtin_amdgcn_global_load_lds((const AS1 void*)(pA1 + t * BK),
            (AS3 void*)(base + wave * 1024 + 512), 16, 0, 0);
        __builtin_amdgcn_global_load_lds((const AS1 void*)(pB0 + t * BK),
            (AS3 void*)(base + 4096 + wave * 1024), 16, 0, 0);
        __builtin_amdgcn_global_load_lds((const AS1 void*)(pB1 + t * BK),
            (AS3 void*)(base + 4096 + wave * 1024 + 512), 16, 0, 0);
    };

    // prologue: stage slices 0,1; certify slice 0 (slice 1's 4 loads in flight)
    stage(0, 0);
    stage(1, 1);
    asm volatile("s_waitcnt vmcnt(4)" ::: "memory");
    __builtin_amdgcn_s_barrier();
    __builtin_amdgcn_sched_barrier(0);

    #pragma unroll
    for (int t = 0; t < NSLICE; ++t) {
        const int slot = t % RING;
        if (t + 2 < NSLICE) stage(t + 2, (t + 2) % RING);

        bf16x8 af[4], bf4[4];
        #pragma unroll
        for (int mf = 0; mf < 4; ++mf)
            af[mf] = *reinterpret_cast<const bf16x8*>(&lds[slot][aOff[mf]]);
        #pragma unroll
        for (int nf = 0; nf < 4; ++nf)
            bf4[nf] = *reinterpret_cast<const bf16x8*>(&lds[slot][bOff[nf]]);

        __builtin_amdgcn_s_setprio(1);
        #pragma unroll
        for (int mf = 0; mf < 4; ++mf)
            #pragma unroll
            for (int nf = 0; nf < 4; ++nf)
                acc[mf][nf] = __builtin_amdgcn_mfma_f32_16x16x32_bf16(
                    af[mf], bf4[nf], acc[mf][nf], 0, 0, 0);
        __builtin_amdgcn_s_setprio(0);

        if (t + 1 < NSLICE) {
            if (t + 2 < NSLICE) { asm volatile("s_waitcnt vmcnt(4)" ::: "memory"); }
            else                { asm volatile("s_waitcnt vmcnt(0)" ::: "memory"); }
            __builtin_amdgcn_s_barrier();
            __builtin_amdgcn_sched_barrier(0);
        }
    }

    const float INF = __builtin_inff();

    // ---- row-side: rows I, min over this wave's 64 cols ----
    // C/D 16x16x32 layout: col = lane&15, row = (lane>>4)*4 + reg  (verified r1-3)
    float bb[4];
    #pragma unroll
    for (int nf = 0; nf < 4; ++nf) bb[nf] = beta[jbase + wc * 64 + nf * 16 + tl];

    #pragma unroll
    for (int mf = 0; mf < 4; ++mf) {
        int grow0 = ibase + wr * 64 + mf * 16 + g * 4;
        float mn0 = INF, mn1 = INF, mn2 = INF, mn3 = INF;
        #pragma unroll
        for (int nf = 0; nf < 4; ++nf) {
            int gcol = jbase + wc * 64 + nf * 16 + tl;
            float c0 = fmaf(-2.f, acc[mf][nf][0], bb[nf]);
            float c1 = fmaf(-2.f, acc[mf][nf][1], bb[nf]);
            float c2 = fmaf(-2.f, acc[mf][nf][2], bb[nf]);
            float c3 = fmaf(-2.f, acc[mf][nf][3], bb[nf]);
            if (grow0 + 0 == gcol) c0 = INF;
            if (grow0 + 1 == gcol) c1 = INF;
            if (grow0 + 2 == gcol) c2 = INF;
            if (grow0 + 3 == gcol) c3 = INF;
            mn0 = fminf(mn0, c0);
            mn1 = fminf(mn1, c1);
            mn2 = fminf(mn2, c2);
            mn3 = fminf(mn3, c3);
        }
        #pragma unroll
        for (int mask = 1; mask < 16; mask <<= 1) {
            mn0 = fminf(mn0, __shfl_xor(mn0, mask, 64));
            mn1 = fminf(mn1, __shfl_xor(mn1, mask, 64));
            mn2 = fminf(mn2, __shfl_xor(mn2, mask, 64));
            mn3 = fminf(mn3, __shfl_xor(mn3, mask, 64));
        }
        if (tl == 0) {
            float d20 = fmaxf(alpha[grow0 + 0] + DEPS2 + mn0, 0.f);
            float d21 = fmaxf(alpha[grow0 + 1] + DEPS2 + mn1, 0.f);
            float d22 = fmaxf(alpha[grow0 + 2] + DEPS2 + mn2, 0.f);
            float d23 = fmaxf(alpha[grow0 + 3] + DEPS2 + mn3, 0.f);
            atomicMin(dan2 + grow0 + 0, __float_as_uint(d20));
            atomicMin(dan2 + grow0 + 1, __float_as_uint(d21));
            atomicMin(dan2 + grow0 + 2, __float_as_uint(d22));
            atomicMin(dan2 + grow0 + 3, __float_as_uint(d23));
        }
    }

    // ---- col-side (off-diag tiles only): this wave's 64 cols, min over its 64 rows ----
    if (!diag) {
        #pragma unroll
        for (int nf = 0; nf < 4; ++nf) {
            int gcol = jbase + wc * 64 + nf * 16 + tl;
            float cm = INF;
            #pragma unroll
            for (int mf = 0; mf < 4; ++mf) {
                int grow0 = ibase + wr * 64 + mf * 16 + g * 4;
                #pragma unroll
                for (int e = 0; e < 4; ++e) {
                    float c = fmaf(-2.f, acc[mf][nf][e], beta[grow0 + e]);
                    cm = fminf(cm, c);
                }
            }
            cm = fminf(cm, __shfl_xor(cm, 16, 64));
            cm = fminf(cm, __shfl_xor(cm, 32, 64));
            if (g == 0) {
                float d2 = fmaxf(alpha[gcol] + DEPS2 + cm, 0.f);
                atomicMin(dan2 + gcol, __float_as_uint(d2));
            }
        }
    }
}

// ---------------- Kernel 3: final loss reduction ----------------
__global__ __launch_bounds__(1024) void finalize_kernel(
        const float* __restrict__ dap, const unsigned int* __restrict__ dan2,
        float* __restrict__ out, int N) {
    __shared__ float red[16];
    float sum = 0.f;
    for (int i = threadIdx.x; i < N; i += 1024) {
        float dan = sqrtf(__uint_as_float(dan2[i]));
        float v = dap[i] - dan + MARGIN;
        sum += fmaxf(v, 0.f);
    }
    #pragma unroll
    for (int mask = 32; mask; mask >>= 1) sum += __shfl_xor(sum, mask, 64);
    int lane = threadIdx.x & 63, w = threadIdx.x >> 6;
    if (lane == 0) red[w] = sum;
    __syncthreads();
    if (threadIdx.x == 0) {
        float tot = 0.f;
        #pragma unroll
        for (int k = 0; k < 16; ++k) tot += red[k];
        out[0] = tot / (float)N;
    }
}

extern "C" void kernel_launch(void* const* d_in, const int* in_sizes, int n_in,
                              void* d_out, int out_size, void* d_ws, size_t ws_size,
                              hipStream_t stream) {
    const float* anchor   = (const float*)d_in[0];
    const float* positive = (const float*)d_in[1];
    int N = in_sizes[0] / DIM;   // 8192
    float* out = (float*)d_out;

    char* ws = (char*)d_ws;
    float* alpha = (float*)ws;
    float* beta  = alpha + N;
    float* dap   = beta + N;
    unsigned int* dan2 = (unsigned int*)(dap + N);
    u16* Abf = (u16*)(dan2 + N);   // N*DIM bf16 = 8.4 MB

    prep_kernel<<<N / 4, 256, 0, stream>>>(anchor, positive, Abf, alpha, beta, dap, dan2, N);
    int nbt = N >> 7;                       // 64 tiles of 128
    int ntri = nbt * (nbt + 1) / 2;         // 2080 blocks (= 8 * 260), it <= jt
    gemm_min_kernel<<<ntri, 256, 0, stream>>>(Abf, alpha, beta, dan2, N);
    finalize_kernel<<<1, 1024, 0, stream>>>(dap, dan2, out, N);
}